// Round 9
// baseline (1380.536 us; speedup 1.0000x reference)
//
#include <hip/hip_runtime.h>
#include <hip/hip_bf16.h>
#include <stdint.h>

// GraphCON-GCN on MI355X.
// Algebra: with DT=ALPHA=GAMMA=1, Xs_{l+1} = relu(gcn+res); Y drops out.
// z = (A.Xs) Wc^T + (dinv^2-1) Xs Wc^T + Xs Wr^T + (b_c+b_r)  [self-term folded
// into the GEMM in-register]. State fp16 (XsH); agg gathers fp16, U fp16.
// CSR build: scattered 4B stores cost a full 64B line each (round-8 lesson:
// WRITE_SIZE ~= E*64 regardless of L2 windowing). So build via LDS-assembled
// coalesced bursts: k_bin (bucket by dst>>9, burst-flush to bucket regions),
// k_bscan (bucket bases), k_build (per-bucket deg/scan/rp/dinv + LDS col
// window dumped coalesced). col record = src only; agg loads dinv[src].
// GEMM: fp16 MFMA, ONE weight matrix staged at a time (32KB LDS -> 4 blk/CU).
// Decode fused into final GEMM; pooling via LDS histogram.

#define HD 128
#define BSH 9                 // bucket shift: 512 nodes per bucket
#define BSTRIDE 16384         // records per bucket region (mean ~8192)
#define BCAP 12288            // LDS col window capacity (48KB)

typedef __attribute__((ext_vector_type(4))) float f32x4;
typedef __attribute__((ext_vector_type(8))) float f32x8;
typedef __attribute__((ext_vector_type(8))) _Float16 f16x8;

// ---- CSR build: phase A — bin edges by dst>>BSH with LDS burst staging -----
__global__ __launch_bounds__(256) void k_bin(const int* __restrict__ src,
                                             const int* __restrict__ dst, int E,
                                             unsigned* __restrict__ tmp,
                                             int* __restrict__ gcur, int nbuck){
  __shared__ unsigned stage[256 * 32];
  __shared__ int lcnt[256];
  int t = threadIdx.x;
  lcnt[t] = 0;
  __syncthreads();
  int base = blockIdx.x * 2048;
#pragma unroll
  for (int k = 0; k < 8; ++k){
    int e = base + k * 256 + t;
    if (e < E){
      int d = dst[e], s = src[e];
      unsigned rec = ((unsigned)(d & ((1 << BSH) - 1)) << 17) | (unsigned)s;
      int b = d >> BSH;
      int slot = atomicAdd(&lcnt[b], 1);
      if (slot < 32) stage[b * 32 + slot] = rec;
      else {                                  // ~never (Poisson(10.4) > 32)
        int g = atomicAdd(&gcur[b], 1);
        if (g < BSTRIDE) tmp[(size_t)b * BSTRIDE + g] = rec;
      }
    }
  }
  __syncthreads();
  // wave-cooperative flush: wave w handles buckets w, w+4, ...
  int wv = t >> 6, lane = t & 63;
  for (int b = wv; b < nbuck; b += 4){
    int cnt = min(lcnt[b], 32);
    if (cnt == 0) continue;
    int gbase = 0;
    if (lane == 0) gbase = atomicAdd(&gcur[b], cnt);
    gbase = __shfl(gbase, 0, 64);
    if (lane < cnt && gbase + lane < BSTRIDE)
      tmp[(size_t)b * BSTRIDE + gbase + lane] = stage[b * 32 + lane];
  }
}

// ---- phase A2: tiny exclusive scan of bucket counts ------------------------
__global__ __launch_bounds__(256) void k_bscan(const int* __restrict__ gcur,
                                               int* __restrict__ bbase, int nbuck,
                                               int* __restrict__ rp, int N, int E){
  __shared__ int sm[256];
  int t = threadIdx.x;
  sm[t] = (t < nbuck) ? gcur[t] : 0;
  __syncthreads();
  for (int off = 1; off < 256; off <<= 1){
    int v = (t >= off) ? sm[t - off] : 0;
    __syncthreads();
    sm[t] += v;
    __syncthreads();
  }
  if (t < nbuck) bbase[t] = (t == 0) ? 0 : sm[t - 1];
  if (t == 0) rp[N] = E;
}

// ---- phase B: per-bucket deg/rp/dinv + line-assembled col ------------------
__global__ __launch_bounds__(256) void k_build(const unsigned* __restrict__ tmp,
                                               const int* __restrict__ gcur,
                                               const int* __restrict__ bbase,
                                               int* __restrict__ rp,
                                               float* __restrict__ dinv,
                                               unsigned* __restrict__ col, int N){
  __shared__ unsigned lcol[BCAP];
  __shared__ int deg[512], rpl[512], cur[512];
  __shared__ int ps[256];
  int b = blockIdx.x, t = threadIdx.x;
  int lo = b << BSH;
  int nn = min(512, N - lo);
  int count = min(gcur[b], BCAP);
  int gbase = bbase[b];
  for (int i = t; i < 512; i += 256){ deg[i] = 0; cur[i] = 0; }
  __syncthreads();
  const unsigned* trec = tmp + (size_t)b * BSTRIDE;
  for (int i = t; i < count; i += 256)
    atomicAdd(&deg[trec[i] >> 17], 1);
  __syncthreads();
  // exclusive scan of deg[0..511]: 2 elems/thread + 256-wide Hillis-Steele
  int a0 = deg[2 * t], a1 = deg[2 * t + 1];
  ps[t] = a0 + a1;
  __syncthreads();
  for (int off = 1; off < 256; off <<= 1){
    int v = (t >= off) ? ps[t - off] : 0;
    __syncthreads();
    ps[t] += v;
    __syncthreads();
  }
  int excl = (t == 0) ? 0 : ps[t - 1];
  rpl[2 * t] = excl;
  rpl[2 * t + 1] = excl + a0;
  __syncthreads();
  for (int i = t; i < nn; i += 256){
    rp[lo + i] = gbase + rpl[i];
    dinv[lo + i] = rsqrtf((float)deg[i] + 1.0f);
  }
  for (int i = t; i < count; i += 256){
    unsigned r = trec[i];
    int d = r >> 17;
    int pos = rpl[d] + atomicAdd(&cur[d], 1);
    if (pos < BCAP) lcol[pos] = r & 0x1FFFFu;
  }
  __syncthreads();
  for (int i = t; i < count; i += 256) col[gbase + i] = lcol[i];
}

// ---- weight prep: fp32 -> fp16 (RTN), bias sum -----------------------------
__global__ __launch_bounds__(256) void k_prep_w(const float* __restrict__ Wc,
                                                const float* __restrict__ Wr,
                                                const float* __restrict__ We,
                                                const float* __restrict__ bc,
                                                const float* __restrict__ br,
                                                _Float16* __restrict__ WcF,
                                                _Float16* __restrict__ WrF,
                                                _Float16* __restrict__ WeF,
                                                float* __restrict__ bias_sum){
  int i = blockIdx.x * 256 + threadIdx.x;
  if (i < HD * HD){
    WcF[i] = (_Float16)Wc[i];
    WrF[i] = (_Float16)Wr[i];
    WeF[i] = (_Float16)We[i];
  }
  if (i < HD) bias_sum[i] = bc[i] + br[i];
}

// ---- per-layer aggregation: U = dinv[dst] * sum_e dinv[src]*XsH[src] -------
// One wave per node. Quarter-wave per edge; lane gathers f16x8 (16B);
// 16 lanes * 16B = 256B row. 4x unroll => 16 gathers in flight per wave.
__global__ __launch_bounds__(256) void k_agg(const _Float16* __restrict__ XsH,
                                             const float* __restrict__ dinv,
                                             const int* __restrict__ rp,
                                             const unsigned* __restrict__ col,
                                             _Float16* __restrict__ U,
                                             int N){
  int w = threadIdx.x >> 6;
  int lane = threadIdx.x & 63;
  int q = lane >> 4;       // edge slot 0..3
  int ql = lane & 15;      // channel group: cols ql*8 .. ql*8+7
  int node = blockIdx.x * 4 + w;
  if (node >= N) return;

  float acc[8];
#pragma unroll
  for (int i = 0; i < 8; ++i) acc[i] = 0.f;

  int b = rp[node], e = rp[node + 1];
  int j = b + q;
  for (; j + 12 < e; j += 16){
    unsigned r0 = col[j];
    unsigned r1 = col[j + 4];
    unsigned r2 = col[j + 8];
    unsigned r3 = col[j + 12];
    float w0 = dinv[r0];
    float w1 = dinv[r1];
    float w2 = dinv[r2];
    float w3 = dinv[r3];
    f16x8 v0 = ((const f16x8*)(XsH + (size_t)r0 * HD))[ql];
    f16x8 v1 = ((const f16x8*)(XsH + (size_t)r1 * HD))[ql];
    f16x8 v2 = ((const f16x8*)(XsH + (size_t)r2 * HD))[ql];
    f16x8 v3 = ((const f16x8*)(XsH + (size_t)r3 * HD))[ql];
#pragma unroll
    for (int i = 0; i < 8; ++i) acc[i] = fmaf(w0, (float)v0[i], acc[i]);
#pragma unroll
    for (int i = 0; i < 8; ++i) acc[i] = fmaf(w1, (float)v1[i], acc[i]);
#pragma unroll
    for (int i = 0; i < 8; ++i) acc[i] = fmaf(w2, (float)v2[i], acc[i]);
#pragma unroll
    for (int i = 0; i < 8; ++i) acc[i] = fmaf(w3, (float)v3[i], acc[i]);
  }
  for (; j < e; j += 4){
    unsigned r0 = col[j];
    float w0 = dinv[r0];
    f16x8 v0 = ((const f16x8*)(XsH + (size_t)r0 * HD))[ql];
#pragma unroll
    for (int i = 0; i < 8; ++i) acc[i] = fmaf(w0, (float)v0[i], acc[i]);
  }

  float dn = dinv[node];
#pragma unroll
  for (int i = 0; i < 8; ++i){
    acc[i] += __shfl_xor(acc[i], 16, 64);
    acc[i] += __shfl_xor(acc[i], 32, 64);
    acc[i] *= dn;
  }
  if (q == 0){
    f16x8 o;
#pragma unroll
    for (int i = 0; i < 8; ++i) o[i] = (_Float16)acc[i];
    ((f16x8*)(U + (size_t)node * HD))[ql] = o;
  }
}

// ---- fused fp16 GEMM, ONE weight matrix staged at a time (32KB LDS) --------
// two=false: out = cvt16(A1f) We^T + bias (encoder; A1f fp32).
// two=true:  pass A: acc += (U + (dinv^2-1)XsH) Wc^T; restage; pass B:
//            acc += XsH Wr^T; out = relu(acc + bias). Writes XsH fp16.
// decode: skip stores, val[row] = dot(out_row, Wd) + bd[0].
__global__ __launch_bounds__(256) void k_gemm(
    const float* __restrict__ A1f,            // encoder input x (fp32) or null
    const _Float16* __restrict__ A1h,         // U (fp16) or null
    const _Float16* A2h,                      // XsH (aliases outXsH) or null
    const _Float16* __restrict__ W1,          // WcF or WeF
    const _Float16* __restrict__ W2,          // WrF or null
    const float* __restrict__ dinvp,
    const float* __restrict__ bias,
    _Float16* outXsH,
    const float* __restrict__ Wd, const float* __restrict__ bd,
    float* __restrict__ val,
    int N, int relu, int decode){
  __shared__ _Float16 wsm[HD * HD];           // 32KB: [row][slot^]
  f16x8* smv = (f16x8*)wsm;
  int t = threadIdx.x;

  // stage W1 (swizzled)
  {
    const f16x8* g1 = (const f16x8*)W1;
    for (int i = t; i < HD * HD / 8; i += 256){
      int row = i >> 4, slot = i & 15;
      smv[(row << 4) | (slot ^ (row & 7))] = g1[i];
    }
  }
  __syncthreads();

  int wid = blockIdx.x * 4 + (t >> 6);
  int row0 = wid * 32;
  bool act = (row0 < N);
  int rowb = act ? row0 : 0;
  int lane = t & 63;
  int r = lane & 15;
  int kg = lane >> 4;

  f32x4 acc[2][8];
#pragma unroll
  for (int s = 0; s < 2; ++s)
#pragma unroll
    for (int c = 0; c < 8; ++c) acc[s][c] = (f32x4)0.0f;

  const bool two = (A2h != nullptr);
  float sr[2] = {0.f, 0.f};
  if (two){
#pragma unroll
    for (int s = 0; s < 2; ++s){
      float d = dinvp[rowb + s * 16 + r];
      sr[s] = d * d - 1.0f;
    }
  }

  // ---- pass A: A1 (fold) x W1 ----
#pragma unroll
  for (int kst = 0; kst < 4; ++kst){
    int k0 = kst * 32 + kg * 8;
    f16x8 a1[2];
#pragma unroll
    for (int s = 0; s < 2; ++s){
      size_t ao = (size_t)(rowb + s * 16 + r) * HD + k0;
      if (two){
        f16x8 uh = *(const f16x8*)(A1h + ao);
        f16x8 xv = *(const f16x8*)(A2h + ao);
#pragma unroll
        for (int i = 0; i < 8; ++i)
          a1[s][i] = (_Float16)fmaf(sr[s], (float)xv[i], (float)uh[i]);
      } else {
        f32x8 u = *(const f32x8*)(A1f + ao);
#pragma unroll
        for (int i = 0; i < 8; ++i) a1[s][i] = (_Float16)u[i];
      }
    }
    int swz = (kst * 4 + kg) ^ (r & 7);
#pragma unroll
    for (int ct = 0; ct < 8; ++ct){
      f16x8 b1 = smv[((ct * 16 + r) << 4) | swz];
#pragma unroll
      for (int s = 0; s < 2; ++s)
        acc[s][ct] = __builtin_amdgcn_mfma_f32_16x16x32_f16(a1[s], b1, acc[s][ct], 0, 0, 0);
    }
  }

  // ---- pass B: XsH x W2 ----
  if (two){
    __syncthreads();                          // everyone done reading W1
    const f16x8* g2 = (const f16x8*)W2;
    for (int i = t; i < HD * HD / 8; i += 256){
      int row = i >> 4, slot = i & 15;
      smv[(row << 4) | (slot ^ (row & 7))] = g2[i];
    }
    __syncthreads();
#pragma unroll
    for (int kst = 0; kst < 4; ++kst){
      int k0 = kst * 32 + kg * 8;
      f16x8 a2[2];
#pragma unroll
      for (int s = 0; s < 2; ++s){
        size_t ao = (size_t)(rowb + s * 16 + r) * HD + k0;
        a2[s] = *(const f16x8*)(A2h + ao);
      }
      int swz = (kst * 4 + kg) ^ (r & 7);
#pragma unroll
      for (int ct = 0; ct < 8; ++ct){
        f16x8 b2 = smv[((ct * 16 + r) << 4) | swz];
#pragma unroll
        for (int s = 0; s < 2; ++s)
          acc[s][ct] = __builtin_amdgcn_mfma_f32_16x16x32_f16(a2[s], b2, acc[s][ct], 0, 0, 0);
      }
    }
  }

  // epilogue: C/D layout col = lane&15, row = kg*4 + reg
  float rowp[2][4] = {{0.f,0.f,0.f,0.f},{0.f,0.f,0.f,0.f}};
#pragma unroll
  for (int s = 0; s < 2; ++s){
#pragma unroll
    for (int ct = 0; ct < 8; ++ct){
      int cc = ct * 16 + r;
      float bv = bias[cc];
      float wdv = decode ? Wd[cc] : 0.f;
#pragma unroll
      for (int j = 0; j < 4; ++j){
        float v = acc[s][ct][j] + bv;
        if (relu) v = fmaxf(v, 0.0f);
        if (decode){
          rowp[s][j] += v * wdv;
        } else if (act){
          int rr = row0 + s * 16 + kg * 4 + j;
          outXsH[(size_t)rr * HD + cc] = (_Float16)v;
        }
      }
    }
  }
  if (decode && act){
    float bd0 = bd[0];
#pragma unroll
    for (int s = 0; s < 2; ++s)
#pragma unroll
      for (int j = 0; j < 4; ++j){
        float tt = rowp[s][j];
        tt += __shfl_xor(tt, 1, 64);
        tt += __shfl_xor(tt, 2, 64);
        tt += __shfl_xor(tt, 4, 64);
        tt += __shfl_xor(tt, 8, 64);
        if (r == 0) val[row0 + s * 16 + kg * 4 + j] = tt + bd0;
      }
  }
}

// ---- pooling: LDS histogram per block, few global atomics ------------------
#define POOL_CHUNK 1024
__global__ __launch_bounds__(256) void k_pool(const float* __restrict__ val,
                                              const int* __restrict__ batch,
                                              float* __restrict__ out, int N, int G){
  __shared__ float acc[4096];
  int t = threadIdx.x;
  int lo = blockIdx.x * POOL_CHUNK;
  int hi = min(lo + POOL_CHUNK, N);
  if (G <= 4096){
    for (int i = t; i < G; i += 256) acc[i] = 0.f;
    __syncthreads();
    for (int i = lo + t; i < hi; i += 256) atomicAdd(&acc[batch[i]], val[i]);
    __syncthreads();
    for (int i = t; i < G; i += 256){
      float v = acc[i];
      if (v != 0.f) atomicAdd(&out[i], v);
    }
  } else {
    for (int i = lo + t; i < hi; i += 256) atomicAdd(&out[batch[i]], val[i]);
  }
}

// ---- launcher ---------------------------------------------------------------
extern "C" void kernel_launch(void* const* d_in, const int* in_sizes, int n_in,
                              void* d_out, int out_size, void* d_ws, size_t ws_size,
                              hipStream_t stream){
  const float* x      = (const float*)d_in[0];
  const int*   ei     = (const int*)d_in[1];
  const int*   batch  = (const int*)d_in[2];
  const float* W_enc  = (const float*)d_in[3];
  const float* b_enc  = (const float*)d_in[4];
  const float* W_conv = (const float*)d_in[5];
  const float* b_conv = (const float*)d_in[6];
  const float* W_res  = (const float*)d_in[7];
  const float* b_res  = (const float*)d_in[8];
  const float* W_dec  = (const float*)d_in[9];
  const float* b_dec  = (const float*)d_in[10];

  const int N = in_sizes[0] / HD;
  const int E = in_sizes[1] / 2;
  const int nbuck = (N + (1 << BSH) - 1) >> BSH;   // <= 256 for N <= 131072
  float* out = (float*)d_out;

  char* ws = (char*)d_ws;
  size_t off = 0;
  auto alloc = [&](size_t bytes) -> char* {
    char* p = ws + off;
    off += (bytes + 255) & ~(size_t)255;
    return p;
  };
  int*   rp    = (int*)  alloc(((size_t)N + 1) * 4);
  float* dinv  = (float*)alloc((size_t)N * 4);
  int*   gcur  = (int*)  alloc((size_t)nbuck * 4);
  int*   bbase = (int*)  alloc((size_t)nbuck * 4);
  unsigned* tmp= (unsigned*)alloc((size_t)nbuck * BSTRIDE * 4);
  unsigned* col= (unsigned*)alloc((size_t)E * 4);
  _Float16* XsH= (_Float16*)alloc((size_t)N * HD * 2);
  _Float16* U  = (_Float16*)alloc((size_t)N * HD * 2);
  float* val   = (float*)alloc((size_t)N * 4);
  _Float16* WcF = (_Float16*)alloc((size_t)HD * HD * 2);
  _Float16* WrF = (_Float16*)alloc((size_t)HD * HD * 2);
  _Float16* WeF = (_Float16*)alloc((size_t)HD * HD * 2);
  float* bias_sum = (float*)alloc((size_t)HD * 4);

  hipMemsetAsync(gcur, 0, (size_t)nbuck * 4, stream);
  hipMemsetAsync(out, 0, (size_t)out_size * 4, stream);

  const int* src = ei;
  const int* dst = ei + E;

  k_bin  <<<(E + 2047) / 2048, 256, 0, stream>>>(src, dst, E, tmp, gcur, nbuck);
  k_bscan<<<1, 256, 0, stream>>>(gcur, bbase, nbuck, rp, N, E);
  k_build<<<nbuck, 256, 0, stream>>>(tmp, gcur, bbase, rp, dinv, col, N);
  k_prep_w<<<(HD * HD + 255) / 256, 256, 0, stream>>>(W_conv, W_res, W_enc, b_conv, b_res,
                                                      WcF, WrF, WeF, bias_sum);

  int gemm_blocks = ((N + 31) / 32 + 3) / 4;
  int node_blocks = (N + 3) / 4;

  // encoder: XsH = fp16(x @ W_enc^T + b_enc)   (no relu, no self-fold)
  k_gemm<<<gemm_blocks, 256, 0, stream>>>(x, nullptr, nullptr, WeF, nullptr,
                                          nullptr, b_enc, XsH,
                                          nullptr, nullptr, nullptr, N, 0, 0);

  for (int l = 0; l < 5; ++l){
    k_agg<<<node_blocks, 256, 0, stream>>>(XsH, dinv, rp, col, U, N);
    int last = (l == 4);
    k_gemm<<<gemm_blocks, 256, 0, stream>>>(nullptr, U, XsH, WcF, WrF,
                                            dinv, bias_sum, XsH,
                                            W_dec, b_dec, val, N, 1, last);
  }

  k_pool<<<(N + POOL_CHUNK - 1) / POOL_CHUNK, 256, 0, stream>>>(val, batch, out, N, out_size);
}

// Round 10
// 648.846 us; speedup vs baseline: 2.1277x; 2.1277x over previous
//
#include <hip/hip_runtime.h>
#include <hip/hip_bf16.h>
#include <stdint.h>

// GraphCON-GCN on MI355X.
// Algebra: with DT=ALPHA=GAMMA=1, Xs_{l+1} = relu(gcn+res); Y drops out.
// z = (A.Xs) Wc^T + (dinv^2-1) Xs Wc^T + Xs Wr^T + (b_c+b_r)  [self-term folded
// into the GEMM in-register]. State fp16 (XsH); agg gathers fp16, U fp16.
// Edge record = 4B: (deg+1)<<18 | src; dinv[src]=rsqrt(deg+1) recomputed
// bit-exactly in agg, dinv[dst] factored out of the edge loop.
// CSR build: simple one-pass deg + 3-phase scan + one-pass fill (r9 post-
// mortem: LDS bucket binning = 852us pathological; L2 windowing (r8) = no
// effect; line-granular scatter-write amplification ~64B/edge is the
// accepted floor at ~82us).
// GEMM: fp16 MFMA (16x16x32_f16, fp32 accum), ONE weight matrix LDS-staged
// at a time (32KB -> 4 blk/CU). Decode fused into final GEMM; LDS-hist pool.

#define HD 128
#define SCHUNK 2048    // scan elements per block (256 thr * 8)

typedef __attribute__((ext_vector_type(4))) float f32x4;
typedef __attribute__((ext_vector_type(8))) float f32x8;
typedef __attribute__((ext_vector_type(8))) _Float16 f16x8;

// ---- CSR build ------------------------------------------------------------
__global__ __launch_bounds__(256) void k_deg(const int* __restrict__ dst, int E,
                                             int* __restrict__ cnt){
  int e = blockIdx.x * 256 + threadIdx.x;
  if (e < E) atomicAdd(&cnt[dst[e]], 1);
}

__global__ __launch_bounds__(256) void k_scan_part(const int* __restrict__ cnt,
                                                   int* __restrict__ bsum, int N){
  __shared__ int red[256];
  int t = threadIdx.x;
  int lo = blockIdx.x * SCHUNK + t * 8;
  int s = 0;
#pragma unroll
  for (int k = 0; k < 8; ++k){
    int i = lo + k;
    s += (i < N) ? cnt[i] : 0;
  }
  red[t] = s;
  __syncthreads();
  for (int off = 128; off > 0; off >>= 1){
    if (t < off) red[t] += red[t + off];
    __syncthreads();
  }
  if (t == 0) bsum[blockIdx.x] = red[0];
}

__global__ __launch_bounds__(1024) void k_scan_mid(const int* __restrict__ bsum,
                                                   int* __restrict__ boff, int nb,
                                                   int* __restrict__ rp, int N, int E){
  __shared__ int part[1024];
  int t = threadIdx.x;
  part[t] = (t < nb) ? bsum[t] : 0;
  __syncthreads();
  for (int off = 1; off < 1024; off <<= 1){
    int v = (t >= off) ? part[t - off] : 0;
    __syncthreads();
    part[t] += v;
    __syncthreads();
  }
  if (t < nb) boff[t] = (t == 0) ? 0 : part[t - 1];
  if (t == 0) rp[N] = E;
}

__global__ __launch_bounds__(256) void k_scan_apply(const int* __restrict__ cnt,
                                                    const int* __restrict__ boff,
                                                    int* __restrict__ rp,
                                                    float* __restrict__ dinv, int N){
  __shared__ int tsum[256];
  int t = threadIdx.x;
  int lo = blockIdx.x * SCHUNK + t * 8;
  int v[8];
  int s = 0;
#pragma unroll
  for (int k = 0; k < 8; ++k){
    int i = lo + k;
    v[k] = (i < N) ? cnt[i] : 0;
    s += v[k];
  }
  tsum[t] = s;
  __syncthreads();
  for (int off = 1; off < 256; off <<= 1){
    int u = (t >= off) ? tsum[t - off] : 0;
    __syncthreads();
    tsum[t] += u;
    __syncthreads();
  }
  int base = boff[blockIdx.x] + ((t == 0) ? 0 : tsum[t - 1]);
#pragma unroll
  for (int k = 0; k < 8; ++k){
    int i = lo + k;
    if (i < N){
      rp[i] = base;
      dinv[i] = rsqrtf((float)v[k] + 1.0f);
      base += v[k];
    }
  }
}

// fill: consumes cnt as cursor (atomicSub). 4B record: (deg1<<18) | src.
__global__ __launch_bounds__(256) void k_fill(const int* __restrict__ src,
                                              const int* __restrict__ dst, int E,
                                              const int* __restrict__ rp,
                                              int* cnt,
                                              const float* __restrict__ dinv,
                                              unsigned* __restrict__ col){
  int e = blockIdx.x * 256 + threadIdx.x;
  if (e >= E) return;
  int s = src[e], d = dst[e];
  int pos = rp[d] + atomicSub(&cnt[d], 1) - 1;
  float di = dinv[s];                       // = rsqrt(deg1), deg1 = deg+1
  int deg1 = (int)(1.0f / (di * di) + 0.5f);
  col[pos] = ((unsigned)deg1 << 18) | (unsigned)s;
}

// ---- weight prep: fp32 -> fp16 (RTN), bias sum -----------------------------
__global__ __launch_bounds__(256) void k_prep_w(const float* __restrict__ Wc,
                                                const float* __restrict__ Wr,
                                                const float* __restrict__ We,
                                                const float* __restrict__ bc,
                                                const float* __restrict__ br,
                                                _Float16* __restrict__ WcF,
                                                _Float16* __restrict__ WrF,
                                                _Float16* __restrict__ WeF,
                                                float* __restrict__ bias_sum){
  int i = blockIdx.x * 256 + threadIdx.x;
  if (i < HD * HD){
    WcF[i] = (_Float16)Wc[i];
    WrF[i] = (_Float16)Wr[i];
    WeF[i] = (_Float16)We[i];
  }
  if (i < HD) bias_sum[i] = bc[i] + br[i];
}

// ---- per-layer aggregation: U = dinv[dst] * sum_e rsqrt(deg1_src)*XsH[src] -
// One wave per node. Quarter-wave per edge; lane gathers f16x8 (16B);
// 16 lanes * 16B = 256B row. 4x unroll => 16 gathers in flight per wave.
__global__ __launch_bounds__(256) void k_agg(const _Float16* __restrict__ XsH,
                                             const float* __restrict__ dinv,
                                             const int* __restrict__ rp,
                                             const unsigned* __restrict__ col,
                                             _Float16* __restrict__ U,
                                             int N){
  int w = threadIdx.x >> 6;
  int lane = threadIdx.x & 63;
  int q = lane >> 4;       // edge slot 0..3
  int ql = lane & 15;      // channel group: cols ql*8 .. ql*8+7
  int node = blockIdx.x * 4 + w;
  if (node >= N) return;

  float acc[8];
#pragma unroll
  for (int i = 0; i < 8; ++i) acc[i] = 0.f;

  int b = rp[node], e = rp[node + 1];
  int j = b + q;
  for (; j + 12 < e; j += 16){
    unsigned r0 = col[j];
    unsigned r1 = col[j + 4];
    unsigned r2 = col[j + 8];
    unsigned r3 = col[j + 12];
    float w0 = rsqrtf((float)(r0 >> 18));
    float w1 = rsqrtf((float)(r1 >> 18));
    float w2 = rsqrtf((float)(r2 >> 18));
    float w3 = rsqrtf((float)(r3 >> 18));
    f16x8 v0 = ((const f16x8*)(XsH + (size_t)(r0 & 0x3FFFFu) * HD))[ql];
    f16x8 v1 = ((const f16x8*)(XsH + (size_t)(r1 & 0x3FFFFu) * HD))[ql];
    f16x8 v2 = ((const f16x8*)(XsH + (size_t)(r2 & 0x3FFFFu) * HD))[ql];
    f16x8 v3 = ((const f16x8*)(XsH + (size_t)(r3 & 0x3FFFFu) * HD))[ql];
#pragma unroll
    for (int i = 0; i < 8; ++i) acc[i] = fmaf(w0, (float)v0[i], acc[i]);
#pragma unroll
    for (int i = 0; i < 8; ++i) acc[i] = fmaf(w1, (float)v1[i], acc[i]);
#pragma unroll
    for (int i = 0; i < 8; ++i) acc[i] = fmaf(w2, (float)v2[i], acc[i]);
#pragma unroll
    for (int i = 0; i < 8; ++i) acc[i] = fmaf(w3, (float)v3[i], acc[i]);
  }
  for (; j < e; j += 4){
    unsigned r0 = col[j];
    float w0 = rsqrtf((float)(r0 >> 18));
    f16x8 v0 = ((const f16x8*)(XsH + (size_t)(r0 & 0x3FFFFu) * HD))[ql];
#pragma unroll
    for (int i = 0; i < 8; ++i) acc[i] = fmaf(w0, (float)v0[i], acc[i]);
  }

  float dn = dinv[node];
#pragma unroll
  for (int i = 0; i < 8; ++i){
    acc[i] += __shfl_xor(acc[i], 16, 64);
    acc[i] += __shfl_xor(acc[i], 32, 64);
    acc[i] *= dn;
  }
  if (q == 0){
    f16x8 o;
#pragma unroll
    for (int i = 0; i < 8; ++i) o[i] = (_Float16)acc[i];
    ((f16x8*)(U + (size_t)node * HD))[ql] = o;
  }
}

// ---- fused fp16 GEMM, ONE weight matrix staged at a time (32KB LDS) --------
// two=false: out = cvt16(A1f) We^T + bias (encoder; A1f fp32).
// two=true:  pass A: acc += (U + (dinv^2-1)XsH) Wc^T; restage; pass B:
//            acc += XsH Wr^T; out = relu(acc + bias). Writes XsH fp16.
// decode: skip stores, val[row] = dot(out_row, Wd) + bd[0].
__global__ __launch_bounds__(256) void k_gemm(
    const float* __restrict__ A1f,            // encoder input x (fp32) or null
    const _Float16* __restrict__ A1h,         // U (fp16) or null
    const _Float16* A2h,                      // XsH (aliases outXsH) or null
    const _Float16* __restrict__ W1,          // WcF or WeF
    const _Float16* __restrict__ W2,          // WrF or null
    const float* __restrict__ dinvp,
    const float* __restrict__ bias,
    _Float16* outXsH,
    const float* __restrict__ Wd, const float* __restrict__ bd,
    float* __restrict__ val,
    int N, int relu, int decode){
  __shared__ _Float16 wsm[HD * HD];           // 32KB: [row][slot^]
  f16x8* smv = (f16x8*)wsm;
  int t = threadIdx.x;

  // stage W1 (swizzled)
  {
    const f16x8* g1 = (const f16x8*)W1;
    for (int i = t; i < HD * HD / 8; i += 256){
      int row = i >> 4, slot = i & 15;
      smv[(row << 4) | (slot ^ (row & 7))] = g1[i];
    }
  }
  __syncthreads();

  int wid = blockIdx.x * 4 + (t >> 6);
  int row0 = wid * 32;
  bool act = (row0 < N);
  int rowb = act ? row0 : 0;
  int lane = t & 63;
  int r = lane & 15;
  int kg = lane >> 4;

  f32x4 acc[2][8];
#pragma unroll
  for (int s = 0; s < 2; ++s)
#pragma unroll
    for (int c = 0; c < 8; ++c) acc[s][c] = (f32x4)0.0f;

  const bool two = (A2h != nullptr);
  float sr[2] = {0.f, 0.f};
  if (two){
#pragma unroll
    for (int s = 0; s < 2; ++s){
      float d = dinvp[rowb + s * 16 + r];
      sr[s] = d * d - 1.0f;
    }
  }

  // ---- pass A: A1 (fold) x W1 ----
#pragma unroll
  for (int kst = 0; kst < 4; ++kst){
    int k0 = kst * 32 + kg * 8;
    f16x8 a1[2];
#pragma unroll
    for (int s = 0; s < 2; ++s){
      size_t ao = (size_t)(rowb + s * 16 + r) * HD + k0;
      if (two){
        f16x8 uh = *(const f16x8*)(A1h + ao);
        f16x8 xv = *(const f16x8*)(A2h + ao);
#pragma unroll
        for (int i = 0; i < 8; ++i)
          a1[s][i] = (_Float16)fmaf(sr[s], (float)xv[i], (float)uh[i]);
      } else {
        f32x8 u = *(const f32x8*)(A1f + ao);
#pragma unroll
        for (int i = 0; i < 8; ++i) a1[s][i] = (_Float16)u[i];
      }
    }
    int swz = (kst * 4 + kg) ^ (r & 7);
#pragma unroll
    for (int ct = 0; ct < 8; ++ct){
      f16x8 b1 = smv[((ct * 16 + r) << 4) | swz];
#pragma unroll
      for (int s = 0; s < 2; ++s)
        acc[s][ct] = __builtin_amdgcn_mfma_f32_16x16x32_f16(a1[s], b1, acc[s][ct], 0, 0, 0);
    }
  }

  // ---- pass B: XsH x W2 ----
  if (two){
    __syncthreads();                          // everyone done reading W1
    const f16x8* g2 = (const f16x8*)W2;
    for (int i = t; i < HD * HD / 8; i += 256){
      int row = i >> 4, slot = i & 15;
      smv[(row << 4) | (slot ^ (row & 7))] = g2[i];
    }
    __syncthreads();
#pragma unroll
    for (int kst = 0; kst < 4; ++kst){
      int k0 = kst * 32 + kg * 8;
      f16x8 a2[2];
#pragma unroll
      for (int s = 0; s < 2; ++s){
        size_t ao = (size_t)(rowb + s * 16 + r) * HD + k0;
        a2[s] = *(const f16x8*)(A2h + ao);
      }
      int swz = (kst * 4 + kg) ^ (r & 7);
#pragma unroll
      for (int ct = 0; ct < 8; ++ct){
        f16x8 b2 = smv[((ct * 16 + r) << 4) | swz];
#pragma unroll
        for (int s = 0; s < 2; ++s)
          acc[s][ct] = __builtin_amdgcn_mfma_f32_16x16x32_f16(a2[s], b2, acc[s][ct], 0, 0, 0);
      }
    }
  }

  // epilogue: C/D layout col = lane&15, row = kg*4 + reg
  float rowp[2][4] = {{0.f,0.f,0.f,0.f},{0.f,0.f,0.f,0.f}};
#pragma unroll
  for (int s = 0; s < 2; ++s){
#pragma unroll
    for (int ct = 0; ct < 8; ++ct){
      int cc = ct * 16 + r;
      float bv = bias[cc];
      float wdv = decode ? Wd[cc] : 0.f;
#pragma unroll
      for (int j = 0; j < 4; ++j){
        float v = acc[s][ct][j] + bv;
        if (relu) v = fmaxf(v, 0.0f);
        if (decode){
          rowp[s][j] += v * wdv;
        } else if (act){
          int rr = row0 + s * 16 + kg * 4 + j;
          outXsH[(size_t)rr * HD + cc] = (_Float16)v;
        }
      }
    }
  }
  if (decode && act){
    float bd0 = bd[0];
#pragma unroll
    for (int s = 0; s < 2; ++s)
#pragma unroll
      for (int j = 0; j < 4; ++j){
        float tt = rowp[s][j];
        tt += __shfl_xor(tt, 1, 64);
        tt += __shfl_xor(tt, 2, 64);
        tt += __shfl_xor(tt, 4, 64);
        tt += __shfl_xor(tt, 8, 64);
        if (r == 0) val[row0 + s * 16 + kg * 4 + j] = tt + bd0;
      }
  }
}

// ---- pooling: LDS histogram per block, few global atomics ------------------
#define POOL_CHUNK 1024
__global__ __launch_bounds__(256) void k_pool(const float* __restrict__ val,
                                              const int* __restrict__ batch,
                                              float* __restrict__ out, int N, int G){
  __shared__ float acc[4096];
  int t = threadIdx.x;
  int lo = blockIdx.x * POOL_CHUNK;
  int hi = min(lo + POOL_CHUNK, N);
  if (G <= 4096){
    for (int i = t; i < G; i += 256) acc[i] = 0.f;
    __syncthreads();
    for (int i = lo + t; i < hi; i += 256) atomicAdd(&acc[batch[i]], val[i]);
    __syncthreads();
    for (int i = t; i < G; i += 256){
      float v = acc[i];
      if (v != 0.f) atomicAdd(&out[i], v);
    }
  } else {
    for (int i = lo + t; i < hi; i += 256) atomicAdd(&out[batch[i]], val[i]);
  }
}

// ---- launcher ---------------------------------------------------------------
extern "C" void kernel_launch(void* const* d_in, const int* in_sizes, int n_in,
                              void* d_out, int out_size, void* d_ws, size_t ws_size,
                              hipStream_t stream){
  const float* x      = (const float*)d_in[0];
  const int*   ei     = (const int*)d_in[1];
  const int*   batch  = (const int*)d_in[2];
  const float* W_enc  = (const float*)d_in[3];
  const float* b_enc  = (const float*)d_in[4];
  const float* W_conv = (const float*)d_in[5];
  const float* b_conv = (const float*)d_in[6];
  const float* W_res  = (const float*)d_in[7];
  const float* b_res  = (const float*)d_in[8];
  const float* W_dec  = (const float*)d_in[9];
  const float* b_dec  = (const float*)d_in[10];

  const int N = in_sizes[0] / HD;
  const int E = in_sizes[1] / 2;
  float* out = (float*)d_out;

  char* ws = (char*)d_ws;
  size_t off = 0;
  auto alloc = [&](size_t bytes) -> char* {
    char* p = ws + off;
    off += (bytes + 255) & ~(size_t)255;
    return p;
  };
  int*   cnt   = (int*)  alloc((size_t)N * 4);
  int*   rp    = (int*)  alloc(((size_t)N + 1) * 4);
  float* dinv  = (float*)alloc((size_t)N * 4);
  int*   bsum  = (int*)  alloc(1024 * 4);
  int*   boff  = (int*)  alloc(1024 * 4);
  unsigned* col= (unsigned*)alloc((size_t)E * 4);
  _Float16* XsH= (_Float16*)alloc((size_t)N * HD * 2);
  _Float16* U  = (_Float16*)alloc((size_t)N * HD * 2);
  float* val   = (float*)alloc((size_t)N * 4);
  _Float16* WcF = (_Float16*)alloc((size_t)HD * HD * 2);
  _Float16* WrF = (_Float16*)alloc((size_t)HD * HD * 2);
  _Float16* WeF = (_Float16*)alloc((size_t)HD * HD * 2);
  float* bias_sum = (float*)alloc((size_t)HD * 4);

  hipMemsetAsync(cnt, 0, (size_t)N * 4, stream);
  hipMemsetAsync(out, 0, (size_t)out_size * 4, stream);

  const int* src = ei;
  const int* dst = ei + E;

  int nb = (N + SCHUNK - 1) / SCHUNK;

  k_deg       <<<(E + 255) / 256, 256, 0, stream>>>(dst, E, cnt);
  k_scan_part <<<nb, 256, 0, stream>>>(cnt, bsum, N);
  k_scan_mid  <<<1, 1024, 0, stream>>>(bsum, boff, nb, rp, N, E);
  k_scan_apply<<<nb, 256, 0, stream>>>(cnt, boff, rp, dinv, N);
  k_fill      <<<(E + 255) / 256, 256, 0, stream>>>(src, dst, E, rp, cnt, dinv, col);
  k_prep_w    <<<(HD * HD + 255) / 256, 256, 0, stream>>>(W_conv, W_res, W_enc, b_conv, b_res,
                                                          WcF, WrF, WeF, bias_sum);

  int gemm_blocks = ((N + 31) / 32 + 3) / 4;
  int node_blocks = (N + 3) / 4;

  // encoder: XsH = fp16(x @ W_enc^T + b_enc)   (no relu, no self-fold)
  k_gemm<<<gemm_blocks, 256, 0, stream>>>(x, nullptr, nullptr, WeF, nullptr,
                                          nullptr, b_enc, XsH,
                                          nullptr, nullptr, nullptr, N, 0, 0);

  for (int l = 0; l < 5; ++l){
    k_agg<<<node_blocks, 256, 0, stream>>>(XsH, dinv, rp, col, U, N);
    int last = (l == 4);
    k_gemm<<<gemm_blocks, 256, 0, stream>>>(nullptr, U, XsH, WcF, WrF,
                                            dinv, bias_sum, XsH,
                                            W_dec, b_dec, val, N, 1, last);
  }

  k_pool<<<(N + POOL_CHUNK - 1) / POOL_CHUNK, 256, 0, stream>>>(val, batch, out, N, out_size);
}